// Round 1
// baseline (481.753 us; speedup 1.0000x reference)
//
#include <hip/hip_runtime.h>

#define B_   128
#define L_   196
#define C_   2048
#define H_   512
#define D_   1024
#define KP   224   // L padded to 7*32
#define ALD  232   // att LDS row stride in bf16 elems (464 B -> conflict-free b128)
#define CT   128   // channel tile per block
#define HM   128   // H chunk
#define NITER 28   // 4 chunks * 7 k-steps

typedef __bf16 bf16x8 __attribute__((ext_vector_type(8)));
typedef __bf16 bf16x4 __attribute__((ext_vector_type(4)));
typedef float  f32x4  __attribute__((ext_vector_type(4)));

// ---------------- Wc -> bf16, transposed [H][KP], K-padded with zeros ----------------
__global__ __launch_bounds__(256) void k_wc(const float* __restrict__ Wc, __bf16* __restrict__ wcb) {
    int tid = blockIdx.x * 256 + threadIdx.x;   // 512*224 = 114688 total
    int hh = tid / KP;
    int k  = tid - hh * KP;
    float v = (k < L_) ? Wc[(size_t)k * H_ + hh] : 0.0f;
    wcb[tid] = (__bf16)v;
}

// ---------------- ph[b][h] = h @ Wh + bh + bc ----------------
__global__ __launch_bounds__(512) void k_ph(const float* __restrict__ h, const float* __restrict__ Wh,
                                            const float* __restrict__ bh, const float* __restrict__ bc,
                                            float* __restrict__ ph_ws) {
    int b0 = blockIdx.x * 4;
    int t = threadIdx.x;
    __shared__ float hs[4][D_];
    for (int idx = t; idx < 4 * D_; idx += 512)
        hs[idx >> 10][idx & (D_ - 1)] = h[(size_t)(b0 + (idx >> 10)) * D_ + (idx & (D_ - 1))];
    __syncthreads();
    float base = bh[t] + bc[t];
    float a0 = base, a1 = base, a2 = base, a3 = base;
#pragma unroll 8
    for (int d = 0; d < D_; ++d) {
        float wv = Wh[(size_t)d * H_ + t];
        a0 += hs[0][d] * wv; a1 += hs[1][d] * wv; a2 += hs[2][d] * wv; a3 += hs[3][d] * wv;
    }
    ph_ws[(size_t)(b0 + 0) * H_ + t] = a0;
    ph_ws[(size_t)(b0 + 1) * H_ + t] = a1;
    ph_ws[(size_t)(b0 + 2) * H_ + t] = a2;
    ph_ws[(size_t)(b0 + 3) * H_ + t] = a3;
}

__device__ __forceinline__ float fast_tanh(float x) {
    x = fminf(fmaxf(x, -15.f), 15.f);
    float e = __builtin_amdgcn_exp2f(x * 2.8853900817779268f);   // exp(2x)
    return 1.0f - 2.0f * __builtin_amdgcn_rcpf(e + 1.0f);
}

// async global->LDS, 16B per lane. dst must be wave-uniform; lanes write dst + lane*16.
__device__ __forceinline__ void stage_wc(const __bf16* __restrict__ wcb, __bf16* dst,
                                         int hc, int kk, int wid, int lane) {
#pragma unroll
    for (int jj = 0; jj < 2; ++jj) {
        int i = wid * 2 + jj;                         // 8 instrs fill 8 KB: [128 rows][32 k]
        const __bf16* g = wcb + (size_t)(hc * HM + i * 16 + (lane >> 2)) * KP + kk * 32 + (lane & 3) * 8;
        __bf16* lp = dst + i * 512;
        __builtin_amdgcn_global_load_lds((__attribute__((address_space(1))) void*)g,
                                         (__attribute__((address_space(3))) void*)lp, 16, 0, 0);
    }
}

// ---------------- scores[b][c] = wa . tanh(Wc^T @ att_b + ph) ----------------
__global__ __launch_bounds__(256) void k_scores(const float* __restrict__ att, const __bf16* __restrict__ wcb,
                                                const float* __restrict__ ph_ws, const float* __restrict__ wa,
                                                const float* __restrict__ ba, float* __restrict__ scores) {
    __shared__ __bf16 att_s[CT * ALD];      // [c][k], k padded 196..223 = 0
    __shared__ __bf16 wc_s[2][HM * 32];     // double-buffered K-step of Wc^T  [h][k]
    __shared__ float  sred[2][2][4][16];

    const int t = threadIdx.x;
    const int lane = t & 63, wid = t >> 6;
    const int wm = wid >> 1, wn = wid & 1;  // wave tile: rows wm*64, cols wn*64
    const int ct = blockIdx.x, b = blockIdx.y;

    stage_wc(wcb, &wc_s[0][0], 0, 0, wid, lane);   // prefetch first Wc step

    // zero-pad att_s K region [196,224)
    {
        const __bf16 z = (__bf16)0.0f;
        bf16x4 z4 = {z, z, z, z};
        for (int idx = t; idx < CT * 7; idx += 256) {
            int c = idx / 7, kq = idx - (idx / 7) * 7;
            *(bf16x4*)&att_s[c * ALD + L_ + kq * 4] = z4;
        }
    }
    // stage att tile fp32 -> bf16, transposed to [c][l] (4x4 micro-transpose per thread)
    {
        const float* abase = att + ((size_t)b * L_) * C_ + ct * CT;
        for (int task = t; task < (CT / 4) * (L_ / 4); task += 256) {   // 32 * 49 tasks
            int cq = task & 31;
            int lq = task >> 5;
            const float* ap = abase + (size_t)(lq * 4) * C_ + cq * 4;
            f32x4 r0 = *(const f32x4*)(ap);
            f32x4 r1 = *(const f32x4*)(ap + C_);
            f32x4 r2 = *(const f32x4*)(ap + 2 * C_);
            f32x4 r3 = *(const f32x4*)(ap + 3 * C_);
#pragma unroll
            for (int i2 = 0; i2 < 4; ++i2) {
                bf16x4 v = {(__bf16)r0[i2], (__bf16)r1[i2], (__bf16)r2[i2], (__bf16)r3[i2]};
                *(bf16x4*)&att_s[(cq * 4 + i2) * ALD + lq * 4] = v;
            }
        }
    }
    __syncthreads();

    // A frag: lane 16b+m holds A[m][8b+i]; wc_s row stride 32 -> contiguous 1KB per frag read
    const int aoff = (wm * 64 + (lane & 15)) * 32 + (lane >> 4) * 8;
    // B frag: lane 16b+n holds B[8b+i][n]; att_s [c][k], stride ALD=232 (bank-uniform)
    const int boff = (wn * 64 + (lane & 15)) * ALD + (lane >> 4) * 8;

    f32x4 zero4 = {0.f, 0.f, 0.f, 0.f};
    f32x4 acc[4][4];
#pragma unroll
    for (int mf = 0; mf < 4; ++mf)
#pragma unroll
        for (int nf = 0; nf < 4; ++nf) acc[mf][nf] = zero4;
    float spart[4] = {0.f, 0.f, 0.f, 0.f};

    for (int i = 0; i < NITER; ++i) {
        const int hc = i / 7;
        const int kk = i - hc * 7;
        const int buf = i & 1;
        if (i + 1 < NITER) {        // prefetch next Wc K-step into other buffer
            const int i2 = i + 1;
            stage_wc(wcb, &wc_s[buf ^ 1][0], i2 / 7, i2 - (i2 / 7) * 7, wid, lane);
        }
        bf16x8 afr[4], bfr[4];
#pragma unroll
        for (int mf = 0; mf < 4; ++mf) afr[mf] = *(const bf16x8*)&wc_s[buf][aoff + mf * 512];
#pragma unroll
        for (int nf = 0; nf < 4; ++nf) bfr[nf] = *(const bf16x8*)&att_s[boff + nf * 16 * ALD + kk * 32];
#pragma unroll
        for (int mf = 0; mf < 4; ++mf)
#pragma unroll
            for (int nf = 0; nf < 4; ++nf)
                acc[mf][nf] = __builtin_amdgcn_mfma_f32_16x16x32_bf16(afr[mf], bfr[nf], acc[mf][nf], 0, 0, 0);

        if (kk == 6) {  // end of H-chunk: tanh + wa reduce, reset acc
            const int rbase = hc * HM + wm * 64 + (lane >> 4) * 4;
#pragma unroll
            for (int mf = 0; mf < 4; ++mf) {
                const int row = rbase + mf * 16;
                f32x4 phv = *(const f32x4*)&ph_ws[(size_t)b * H_ + row];
                f32x4 wav = *(const f32x4*)&wa[row];
#pragma unroll
                for (int nf = 0; nf < 4; ++nf) {
                    f32x4 tv = acc[mf][nf];
                    float ssum = 0.f;
#pragma unroll
                    for (int r = 0; r < 4; ++r) {
                        float x = tv[r] + phv[r];           // C/D: row=(lane>>4)*4+r, col=lane&15
                        ssum += fast_tanh(x) * wav[r];
                    }
                    spart[nf] += ssum;
                    acc[mf][nf] = zero4;
                }
            }
        }
        __syncthreads();   // drains vmcnt (next-stage) + lgkm; protects dbuf reuse
    }

    // reduce over k-groups (lanes xor 16/32), then over wm waves via LDS
#pragma unroll
    for (int nf = 0; nf < 4; ++nf) {
        spart[nf] += __shfl_xor(spart[nf], 16);
        spart[nf] += __shfl_xor(spart[nf], 32);
    }
    if ((lane >> 4) == 0) {
#pragma unroll
        for (int nf = 0; nf < 4; ++nf) sred[wm][wn][nf][lane] = spart[nf];
    }
    __syncthreads();
    if (wm == 0 && (lane >> 4) == 0) {
        const float ba0 = ba[0];
#pragma unroll
        for (int nf = 0; nf < 4; ++nf) {
            float v = sred[0][wn][nf][lane] + sred[1][wn][nf][lane] + ba0;
            scores[(size_t)b * C_ + ct * CT + wn * 64 + nf * 16 + lane] = v;
        }
    }
}

// ---------------- softmax over C per batch ----------------
__global__ __launch_bounds__(256) void k_softmax(const float* __restrict__ sc, float* __restrict__ wout) {
    int b = blockIdx.x, t = threadIdx.x;
    int lane = t & 63, wid = t >> 6;
    const float* sp = sc + (size_t)b * C_;
    float v[8];
#pragma unroll
    for (int j = 0; j < 8; ++j) v[j] = sp[j * 256 + t];
    float m = v[0];
#pragma unroll
    for (int j = 1; j < 8; ++j) m = fmaxf(m, v[j]);
#pragma unroll
    for (int off = 32; off >= 1; off >>= 1) m = fmaxf(m, __shfl_xor(m, off));
    __shared__ float red[4];
    if (lane == 0) red[wid] = m;
    __syncthreads();
    m = fmaxf(fmaxf(red[0], red[1]), fmaxf(red[2], red[3]));
    float s = 0.f;
#pragma unroll
    for (int j = 0; j < 8; ++j) {
        v[j] = __builtin_amdgcn_exp2f((v[j] - m) * 1.4426950408889634f);
        s += v[j];
    }
#pragma unroll
    for (int off = 32; off >= 1; off >>= 1) s += __shfl_xor(s, off);
    __shared__ float red2[4];
    if (lane == 0) red2[wid] = s;
    __syncthreads();
    s = red2[0] + red2[1] + red2[2] + red2[3];
    float inv = __builtin_amdgcn_rcpf(s);
#pragma unroll
    for (int j = 0; j < 8; ++j) wout[(size_t)b * C_ + j * 256 + t] = v[j] * inv;
}

// ---------------- weighted[b][l] = sum_c w[b][c] * att[b][l][c] ----------------
__global__ __launch_bounds__(256) void k_weighted(const float* __restrict__ att, const float* __restrict__ w,
                                                  float* __restrict__ out) {
    int b = blockIdx.y;
    int wid = threadIdx.x >> 6, lane = threadIdx.x & 63;
    int l = blockIdx.x * 4 + wid;                 // 49*4 = 196 exact
    const float* ap = att + ((size_t)b * L_ + l) * C_;
    const float* wp = w + (size_t)b * C_;
    float acc = 0.f;
#pragma unroll
    for (int j = 0; j < 8; ++j) {
        int c = j * 256 + lane * 4;
        f32x4 a4 = *(const f32x4*)(ap + c);
        f32x4 w4 = *(const f32x4*)(wp + c);
        acc += a4[0] * w4[0] + a4[1] * w4[1] + a4[2] * w4[2] + a4[3] * w4[3];
    }
#pragma unroll
    for (int off = 32; off >= 1; off >>= 1) acc += __shfl_xor(acc, off);
    if (lane == 0) out[(size_t)b * L_ + l] = acc;
}

extern "C" void kernel_launch(void* const* d_in, const int* in_sizes, int n_in,
                              void* d_out, int out_size, void* d_ws, size_t ws_size,
                              hipStream_t stream) {
    const float* att = (const float*)d_in[0];
    const float* h   = (const float*)d_in[1];
    const float* Wc  = (const float*)d_in[2];
    const float* bc  = (const float*)d_in[3];
    const float* Wh  = (const float*)d_in[4];
    const float* bh  = (const float*)d_in[5];
    const float* wa  = (const float*)d_in[6];
    const float* ba  = (const float*)d_in[7];
    float* out = (float*)d_out;

    // workspace: ph (128*512 f32) | scores (128*2048 f32) | Wc_bf16 (512*224 bf16) ~ 1.47 MB
    float* ph_ws  = (float*)d_ws;
    float* scores = ph_ws + B_ * H_;
    __bf16* wcb   = (__bf16*)(scores + (size_t)B_ * C_);

    k_wc      <<<dim3((H_ * KP) / 256), 256, 0, stream>>>(Wc, wcb);
    k_ph      <<<dim3(B_ / 4), 512, 0, stream>>>(h, Wh, bh, bc, ph_ws);
    k_scores  <<<dim3(C_ / CT, B_), 256, 0, stream>>>(att, wcb, ph_ws, wa, ba, scores);
    k_softmax <<<dim3(B_), 256, 0, stream>>>(scores, out + B_ * L_);
    k_weighted<<<dim3(L_ / 4, B_), 256, 0, stream>>>(att, out + B_ * L_, out);
}

// Round 3
// 454.822 us; speedup vs baseline: 1.0592x; 1.0592x over previous
//
#include <hip/hip_runtime.h>

#define B_   128
#define L_   196
#define C_   2048
#define H_   512
#define D_   1024
#define KP   224
#define CT   256          // channels (N) per block
#define NITER 14          // 2 hchunks x 7 K-slices

#define SMEM_BYTES (131072 + 4096)   // att_s [256][256] bf16 + sred [8][8][16] f32

typedef __bf16 bf16x8 __attribute__((ext_vector_type(8)));
typedef float  f32x2  __attribute__((ext_vector_type(2)));
typedef float  f32x4  __attribute__((ext_vector_type(4)));

// slot swizzle: physical slot = s ^ permc(c); free (2-way) for both writers and readers
__device__ __forceinline__ int permc(int c) { return ((c >> 2) & 7) ^ ((c & 2) << 1); }

// ---------------- Wc -> bf16 in MFMA-fragment order ----------------
// wcb3 idx = (((kk*32 + rb)*4 + g)*16 + m)*8 + i  holds Wc[k=kk*32+g*8+i][h=rb*16+m]
// => a wave's A-frag (16 rows rb, K-step kk) is 1KB contiguous at lane*16B.
__global__ __launch_bounds__(256) void k_wc3(const float* __restrict__ Wc, __bf16* __restrict__ wcb3) {
    int grp = blockIdx.x * 256 + threadIdx.x;   // 14336 groups of 8
    int m  = grp & 15;
    int g  = (grp >> 4) & 3;
    int rb = (grp >> 6) & 31;
    int kk = grp >> 11;                         // 0..6
    int h  = rb * 16 + m;
    bf16x8 v;
#pragma unroll
    for (int j = 0; j < 8; ++j) {
        int k = kk * 32 + g * 8 + j;
        v[j] = (k < L_) ? (__bf16)Wc[(size_t)k * H_ + h] : (__bf16)0.0f;
    }
    *(bf16x8*)&wcb3[(size_t)grp * 8] = v;
}

// ---------------- ph[b][h] = h @ Wh + bh + bc ----------------
__global__ __launch_bounds__(512) void k_ph(const float* __restrict__ h, const float* __restrict__ Wh,
                                            const float* __restrict__ bh, const float* __restrict__ bc,
                                            float* __restrict__ ph_ws) {
    int b0 = blockIdx.x * 4;
    int t = threadIdx.x;
    __shared__ float hs[4][D_];
    for (int idx = t; idx < 4 * D_; idx += 512)
        hs[idx >> 10][idx & (D_ - 1)] = h[(size_t)(b0 + (idx >> 10)) * D_ + (idx & (D_ - 1))];
    __syncthreads();
    float base = bh[t] + bc[t];
    float a0 = base, a1 = base, a2 = base, a3 = base;
#pragma unroll 8
    for (int d = 0; d < D_; ++d) {
        float wv = Wh[(size_t)d * H_ + t];
        a0 += hs[0][d] * wv; a1 += hs[1][d] * wv; a2 += hs[2][d] * wv; a3 += hs[3][d] * wv;
    }
    ph_ws[(size_t)(b0 + 0) * H_ + t] = a0;
    ph_ws[(size_t)(b0 + 1) * H_ + t] = a1;
    ph_ws[(size_t)(b0 + 2) * H_ + t] = a2;
    ph_ws[(size_t)(b0 + 3) * H_ + t] = a3;
}

__device__ __forceinline__ float fast_tanh(float x) {
    x = fminf(fmaxf(x, -15.f), 15.f);
    float e = __builtin_amdgcn_exp2f(x * 2.8853900817779268f);   // exp(2x)
    return 1.0f - 2.0f * __builtin_amdgcn_rcpf(e + 1.0f);
}

// ---------------- scores[b][c] = wa . tanh(Wc^T @ att_b + ph) ----------------
__global__ __launch_bounds__(512, 2) void k_scores(const float* __restrict__ att, const __bf16* __restrict__ wcb3,
                                                   const float* __restrict__ ph_ws, const float* __restrict__ wa,
                                                   const float* __restrict__ ba, float* __restrict__ scores) {
    extern __shared__ char smem[];
    __bf16* att_s = (__bf16*)smem;              // [256 c][32 slots of 16B], slot XOR-swizzled
    float*  sred  = (float*)(smem + 131072);    // [8 waves][8 nf][16]

    const int t = threadIdx.x, lane = t & 63, wid = t >> 6;
    const int wm = wid >> 1, wn = wid & 1;      // 4 m-waves x 2 n-waves; wave tile 64x128
    const int ct = blockIdx.x, b = blockIdx.y;
    const float* attb = att + ((size_t)b * L_) * C_ + ct * CT;

    // staging role: thread -> (c-pair, slot-in-slice)
    const int cpr = t & 127, sl = t >> 7;       // 128 c-pairs x 4 slots = 512
    const int c0s = cpr * 2;
    const int pmS = permc(c0s);                 // same for c0s and c0s+1

    // B-frag addressing pieces (per lane)
    const int n_ = lane & 15, g_ = lane >> 4;
    const int crow0 = wn * 128 + n_;
    const int t2 = (n_ & 2) << 1;
    const int qb = crow0 >> 2;

    // ---- staging helpers ----
    f32x2 sv[8];
    auto STAGE_LOAD = [&](int kk) {
#pragma unroll
        for (int j = 0; j < 8; ++j) {
            int l = kk * 32 + sl * 8 + j;
            if (l < L_) sv[j] = *(const f32x2*)(attb + (size_t)l * C_ + c0s);
            else { sv[j][0] = 0.f; sv[j][1] = 0.f; }
        }
    };
    auto STAGE_WRITE = [&](int kk) {
        int p = (kk * 4 + sl) ^ pmS;
        bf16x8 r0, r1;
#pragma unroll
        for (int j = 0; j < 8; ++j) { r0[j] = (__bf16)sv[j][0]; r1[j] = (__bf16)sv[j][1]; }
        *(bf16x8*)&att_s[c0s * 256 + p * 8] = r0;
        *(bf16x8*)&att_s[(c0s + 1) * 256 + p * 8] = r1;
    };

    bf16x8 afr[4], afrN[4];
    const __bf16* apA = wcb3 + (size_t)lane * 8;
    auto ALOAD = [&](int it, bf16x8* dst) {
        int hc = (it >= 7) ? 1 : 0;
        int kk = it - hc * 7;
#pragma unroll
        for (int mf = 0; mf < 4; ++mf) {
            int rb = hc * 16 + wm * 4 + mf;    // rows hc*256 + wm*64 + mf*16
            dst[mf] = *(const bf16x8*)(apA + (size_t)(kk * 32 + rb) * 512);
        }
    };

    // ---- prologue: slice 0 + first A-frags ----
    ALOAD(0, afr);
    STAGE_LOAD(0);
    STAGE_WRITE(0);
    __syncthreads();

    f32x4 zero4 = {0.f, 0.f, 0.f, 0.f};
    f32x4 acc[4][8];
#pragma unroll
    for (int mf = 0; mf < 4; ++mf)
#pragma unroll
        for (int nf = 0; nf < 8; ++nf) acc[mf][nf] = zero4;
    float spart[8] = {0.f, 0.f, 0.f, 0.f, 0.f, 0.f, 0.f, 0.f};

    for (int it = 0; it < NITER; ++it) {
        const int hc = (it >= 7) ? 1 : 0;
        const int kk = it - hc * 7;

        if (it + 1 < NITER) ALOAD(it + 1, afrN);     // A prefetch (regs, no barrier needed)
        if (it < 6) STAGE_LOAD(it + 1);              // issue next-slice global reads early

        bf16x8 bfr[8];
        const int sb = kk * 4 + g_;
#pragma unroll
        for (int nf = 0; nf < 8; ++nf) {
            int p = sb ^ (((qb + nf * 4) & 7) ^ t2);
            bfr[nf] = *(const bf16x8*)&att_s[(crow0 + nf * 16) * 256 + p * 8];
        }
#pragma unroll
        for (int mf = 0; mf < 4; ++mf)
#pragma unroll
            for (int nf = 0; nf < 8; ++nf)
                acc[mf][nf] = __builtin_amdgcn_mfma_f32_16x16x32_bf16(afr[mf], bfr[nf], acc[mf][nf], 0, 0, 0);

        if (it < 6) STAGE_WRITE(it + 1);             // write-late: HBM latency hidden under MFMA

        if (kk == 6) {   // end of 256-row H-chunk: tanh + wa reduce, reset acc
            const int rbase = hc * 256 + wm * 64 + g_ * 4;
#pragma unroll
            for (int mf = 0; mf < 4; ++mf) {
                const int row = rbase + mf * 16;
                f32x4 phv = *(const f32x4*)&ph_ws[(size_t)b * H_ + row];
                f32x4 wav = *(const f32x4*)&wa[row];
#pragma unroll
                for (int nf = 0; nf < 8; ++nf) {
                    f32x4 tv = acc[mf][nf];
                    float ss = 0.f;
#pragma unroll
                    for (int r = 0; r < 4; ++r)
                        ss += fast_tanh(tv[r] + phv[r]) * wav[r];   // C/D: col=lane&15, row=g_*4+r
                    spart[nf] += ss;
                    acc[mf][nf] = zero4;
                }
            }
        }

        if (it < 6) __syncthreads();                 // publish slice it+1 (only 6 barriers in loop)

        if (it + 1 < NITER) {
#pragma unroll
            for (int mf = 0; mf < 4; ++mf) afr[mf] = afrN[mf];
        }
    }

    // reduce over k-groups (g_), then across the 4 m-waves via LDS
#pragma unroll
    for (int nf = 0; nf < 8; ++nf) {
        spart[nf] += __shfl_xor(spart[nf], 16);
        spart[nf] += __shfl_xor(spart[nf], 32);
    }
    if (g_ == 0) {
#pragma unroll
        for (int nf = 0; nf < 8; ++nf) sred[(wid * 8 + nf) * 16 + n_] = spart[nf];
    }
    __syncthreads();
    if (wid < 2 && g_ == 0) {                        // wid acts as wn
        const float ba0 = ba[0];
#pragma unroll
        for (int nf = 0; nf < 8; ++nf) {
            float v = ba0;
#pragma unroll
            for (int wmm = 0; wmm < 4; ++wmm) v += sred[((wmm * 2 + wid) * 8 + nf) * 16 + n_];
            scores[(size_t)b * C_ + ct * CT + wid * 128 + nf * 16 + n_] = v;
        }
    }
}

// ---------------- fused: softmax over C  +  weighted[b][l] = sum_c w[c]*att[b][l][c] ----------------
__global__ __launch_bounds__(512) void k_fused(const float* __restrict__ att, const float* __restrict__ sc,
                                               float* __restrict__ out) {
    __shared__ float w_s[C_];
    __shared__ float red[8], red2[8];
    const int b = blockIdx.y, q = blockIdx.x;       // q: l-quarter 0..3
    const int t = threadIdx.x;
    const int lane = t & 63, wid = t >> 6;

    const float* sp = sc + (size_t)b * C_;
    float v[4];
#pragma unroll
    for (int j = 0; j < 4; ++j) v[j] = sp[j * 512 + t];
    float m = fmaxf(fmaxf(v[0], v[1]), fmaxf(v[2], v[3]));
#pragma unroll
    for (int off = 32; off >= 1; off >>= 1) m = fmaxf(m, __shfl_xor(m, off));
    if (lane == 0) red[wid] = m;
    __syncthreads();
#pragma unroll
    for (int w = 0; w < 8; ++w) m = fmaxf(m, red[w]);
    float s = 0.f;
#pragma unroll
    for (int j = 0; j < 4; ++j) {
        v[j] = __builtin_amdgcn_exp2f((v[j] - m) * 1.4426950408889634f);
        s += v[j];
    }
#pragma unroll
    for (int off = 32; off >= 1; off >>= 1) s += __shfl_xor(s, off);
    if (lane == 0) red2[wid] = s;
    __syncthreads();
    s = 0.f;
#pragma unroll
    for (int w = 0; w < 8; ++w) s += red2[w];
    float inv = 1.0f / s;
    float* wout = out + B_ * L_;
#pragma unroll
    for (int j = 0; j < 4; ++j) {
        float wv = v[j] * inv;
        w_s[j * 512 + t] = wv;
        if (q == 0) wout[(size_t)b * C_ + j * 512 + t] = wv;
    }
    __syncthreads();

    // weighted: one wave per l-row, rows [q*49, q*49+49)
    for (int l = wid; l < 49; l += 8) {
        int gl = q * 49 + l;
        const float* ap = att + ((size_t)b * L_ + gl) * C_;
        float acc = 0.f;
#pragma unroll
        for (int j = 0; j < 8; ++j) {
            int c = j * 256 + lane * 4;
            f32x4 a4 = *(const f32x4*)(ap + c);
            f32x4 w4 = *(const f32x4*)&w_s[c];
            acc += a4[0] * w4[0] + a4[1] * w4[1] + a4[2] * w4[2] + a4[3] * w4[3];
        }
#pragma unroll
        for (int off = 32; off >= 1; off >>= 1) acc += __shfl_xor(acc, off);
        if (lane == 0) out[(size_t)b * L_ + gl] = acc;
    }
}

extern "C" void kernel_launch(void* const* d_in, const int* in_sizes, int n_in,
                              void* d_out, int out_size, void* d_ws, size_t ws_size,
                              hipStream_t stream) {
    const float* att = (const float*)d_in[0];
    const float* h   = (const float*)d_in[1];
    const float* Wc  = (const float*)d_in[2];
    const float* bc  = (const float*)d_in[3];
    const float* Wh  = (const float*)d_in[4];
    const float* bh  = (const float*)d_in[5];
    const float* wa  = (const float*)d_in[6];
    const float* ba  = (const float*)d_in[7];
    float* out = (float*)d_out;

    // workspace: ph (128*512 f32) | scores (128*2048 f32) | wcb3 (512*224 bf16)
    float* ph_ws  = (float*)d_ws;
    float* scores = ph_ws + B_ * H_;
    __bf16* wcb3  = (__bf16*)(scores + (size_t)B_ * C_);

    hipFuncSetAttribute((const void*)k_scores, hipFuncAttributeMaxDynamicSharedMemorySize, SMEM_BYTES);

    k_wc3   <<<dim3(56), 256, 0, stream>>>(Wc, wcb3);
    k_ph    <<<dim3(B_ / 4), 512, 0, stream>>>(h, Wh, bh, bc, ph_ws);
    k_scores<<<dim3(C_ / CT, B_), 512, SMEM_BYTES, stream>>>(att, wcb3, ph_ws, wa, ba, scores);
    k_fused <<<dim3(4, B_), 512, 0, stream>>>(att, scores, out);
}

// Round 6
// 440.449 us; speedup vs baseline: 1.0938x; 1.0326x over previous
//
#include <hip/hip_runtime.h>

#define B_   128
#define L_   196
#define C_   2048
#define H_   512
#define D_   1024
#define CT   128          // channels (N) per block
#define NITER 14          // 2 hchunks (256 H-rows) x 7 K-slices (K=32)
#define RSE  224          // att_s row stride in bf16 elems (448B)

typedef __bf16 bf16x8 __attribute__((ext_vector_type(8)));
typedef float  f32x4  __attribute__((ext_vector_type(4)));

// ---------------- fused prep: Wc->fragment-packed bf16  +  ph = h@Wh + bh + bc ----------------
// wcb3: grp = (((kk*32 + rb)*4 + g)*16 + m); wcb3[grp*8 + j] = Wc[k=kk*32+g*8+j][h=rb*16+m]
// => A-frag (kk, rb) is 1KB contiguous; lane 16g+m reads 16B at +lane*16.
__global__ __launch_bounds__(512) void k_prep(const float* __restrict__ Wc, __bf16* __restrict__ wcb3,
                                              const float* __restrict__ h, const float* __restrict__ Wh,
                                              const float* __restrict__ bh, const float* __restrict__ bc,
                                              float* __restrict__ ph_ws) {
    __shared__ float hs[4][D_];
    const int bid = blockIdx.x, t = threadIdx.x;
    if (bid < 28) {                               // ---- Wc fragment packing: 28*512 = 14336 groups
        int grp = bid * 512 + t;
        int m  = grp & 15;
        int g  = (grp >> 4) & 3;
        int rb = (grp >> 6) & 31;
        int kk = grp >> 11;                       // 0..6
        int hh = rb * 16 + m;
        bf16x8 v;
#pragma unroll
        for (int j = 0; j < 8; ++j) {
            int k = kk * 32 + g * 8 + j;
            v[j] = (k < L_) ? (__bf16)Wc[(size_t)k * H_ + hh] : (__bf16)0.0f;
        }
        *(bf16x8*)&wcb3[(size_t)grp * 8] = v;
    } else {                                      // ---- ph: 32 blocks x 4 batches
        int b0 = (bid - 28) * 4;
        for (int idx = t; idx < 4 * D_; idx += 512)
            hs[idx >> 10][idx & (D_ - 1)] = h[(size_t)(b0 + (idx >> 10)) * D_ + (idx & (D_ - 1))];
        __syncthreads();
        float base = bh[t] + bc[t];
        float a0 = base, a1 = base, a2 = base, a3 = base;
#pragma unroll 8
        for (int d = 0; d < D_; ++d) {
            float wv = Wh[(size_t)d * H_ + t];
            a0 += hs[0][d] * wv; a1 += hs[1][d] * wv; a2 += hs[2][d] * wv; a3 += hs[3][d] * wv;
        }
        ph_ws[(size_t)(b0 + 0) * H_ + t] = a0;
        ph_ws[(size_t)(b0 + 1) * H_ + t] = a1;
        ph_ws[(size_t)(b0 + 2) * H_ + t] = a2;
        ph_ws[(size_t)(b0 + 3) * H_ + t] = a3;
    }
}

__device__ __forceinline__ float fast_tanh(float x) {
    // |x| bounded (~30) here; no clamp needed. tanh(x) = 1 - 2/(exp(2x)+1)
    float e = __builtin_amdgcn_exp2f(x * 2.8853900817779268f);
    return fmaf(-2.0f, __builtin_amdgcn_rcpf(e + 1.0f), 1.0f);
}

// raw barrier: publish ds_writes without draining vmcnt (keeps prefetches in flight)
__device__ __forceinline__ void block_sync_lds() {
    asm volatile("s_waitcnt lgkmcnt(0)" ::: "memory");
    __builtin_amdgcn_sched_barrier(0);
    __builtin_amdgcn_s_barrier();
    __builtin_amdgcn_sched_barrier(0);
}

// ---------------- scores[b][c] = wa . tanh(Wc^T @ att_b + ph) ----------------
// att_s: [128 c][7 slices][4 slots of 16B]; physical slot p = s ^ ((c>>1)&3)
// (write: 64 lanes -> 8 lanes/bank-quad = b128 floor; read: same. Verified by enumeration.)
__global__ __launch_bounds__(512, 4) void k_scores(const float* __restrict__ att, const __bf16* __restrict__ wcb3,
                                                   const float* __restrict__ ph_ws, const float* __restrict__ wa,
                                                   const float* __restrict__ ba, float* __restrict__ scores) {
    __shared__ __bf16 att_s[CT * RSE];          // 57,344 B
    __shared__ float  sred[8][4][16];           // 2 KB

    const int t = threadIdx.x, lane = t & 63, wid = t >> 6;
    const int wm = wid >> 1, wn = wid & 1;      // 4 m-waves x 2 n-waves; wave tile 64x64
    const int ct = blockIdx.x, b = blockIdx.y;
    const float* attb = att + ((size_t)b * L_) * C_ + ct * CT;

    // staging role: one channel per thread, one 8-l slot
    const int sc = t & 127, sl = t >> 7;                 // c 0..127, slot 0..3
    const int spdst = sc * RSE + (sl ^ ((sc >> 1) & 3)) * 8;   // + kk*32

    // B-frag addressing
    const int n_ = lane & 15, g_ = lane >> 4;
    const int bbase = (wn * 64 + n_) * RSE + (g_ ^ ((n_ >> 1) & 3)) * 8;   // + nf*16*RSE + kk*32

    const __bf16* apA = wcb3 + (size_t)lane * 8;

    float sv[8];
    bf16x8 afr[4];

    // ---- helpers ----
    auto STAGE_LOAD = [&](int kk) {
#pragma unroll
        for (int j = 0; j < 8; ++j) {
            int l = kk * 32 + sl * 8 + j;
            sv[j] = (l < L_) ? attb[(size_t)l * C_ + sc] : 0.0f;
        }
    };
    auto STAGE_WRITE = [&](int kk) {
        bf16x8 r;
#pragma unroll
        for (int j = 0; j < 8; ++j) r[j] = (__bf16)sv[j];
        *(bf16x8*)&att_s[spdst + kk * 32] = r;
    };
    auto ALOAD = [&](int it) {
        int hc = (it >= 7) ? 1 : 0;
        int kk = it - hc * 7;
#pragma unroll
        for (int mf = 0; mf < 4; ++mf)
            afr[mf] = *(const bf16x8*)(apA + (size_t)(kk * 32 + hc * 16 + wm * 4 + mf) * 512);
    };

    // ---- prologue: slice 0 + first A-frags ----
    STAGE_LOAD(0);
    ALOAD(0);
    STAGE_WRITE(0);
    block_sync_lds();

    f32x4 zero4 = {0.f, 0.f, 0.f, 0.f};
    f32x4 acc[4][4];
#pragma unroll
    for (int mf = 0; mf < 4; ++mf)
#pragma unroll
        for (int nf = 0; nf < 4; ++nf) acc[mf][nf] = zero4;
    float spart[4] = {0.f, 0.f, 0.f, 0.f};

#pragma unroll
    for (int it = 0; it < NITER; ++it) {
        const int hc = (it >= 7) ? 1 : 0;
        const int kk = it - hc * 7;

        if (it < 6) STAGE_LOAD(it + 1);          // issue next-slice global reads first (T14)

        __builtin_amdgcn_s_setprio(1);
#pragma unroll
        for (int nf = 0; nf < 4; ++nf) {
            bf16x8 bfr = *(const bf16x8*)&att_s[bbase + nf * 16 * RSE + kk * 32];
#pragma unroll
            for (int mf = 0; mf < 4; ++mf)
                acc[mf][nf] = __builtin_amdgcn_mfma_f32_16x16x32_bf16(afr[mf], bfr, acc[mf][nf], 0, 0, 0);
        }
        __builtin_amdgcn_s_setprio(0);

        if (it + 1 < NITER) ALOAD(it + 1);       // refill afr after last use (L2-hit latency hidden)
        if (it < 6) STAGE_WRITE(it + 1);         // write-late: counted vmcnt wait on sv only

        if (kk == 6) {   // end of 256-row H-chunk: tanh + wa reduce, reset acc
            const int rbase = hc * 256 + wm * 64 + g_ * 4;
#pragma unroll
            for (int mf = 0; mf < 4; ++mf) {
                const int row = rbase + mf * 16;
                f32x4 phv = *(const f32x4*)&ph_ws[(size_t)b * H_ + row];
                f32x4 wav = *(const f32x4*)&wa[row];
#pragma unroll
                for (int nf = 0; nf < 4; ++nf) {
                    f32x4 tv = acc[mf][nf];
                    float ss = 0.f;
#pragma unroll
                    for (int r = 0; r < 4; ++r)
                        ss += fast_tanh(tv[r] + phv[r]) * wav[r];   // C/D: col=lane&15, row=g_*4+r
                    spart[nf] += ss;
                    acc[mf][nf] = zero4;
                }
            }
        }

        if (it < 6) block_sync_lds();            // publish slice it+1 (lgkm only, vmcnt untouched)
    }

    // reduce over k-quarters (g_), then across the 4 m-waves via LDS
#pragma unroll
    for (int nf = 0; nf < 4; ++nf) {
        spart[nf] += __shfl_xor(spart[nf], 16);
        spart[nf] += __shfl_xor(spart[nf], 32);
    }
    if (g_ == 0) {
#pragma unroll
        for (int nf = 0; nf < 4; ++nf) sred[wid][nf][n_] = spart[nf];
    }
    __syncthreads();
    if (wid < 2 && g_ == 0) {                    // wid acts as wn
        const float ba0 = ba[0];
#pragma unroll
        for (int nf = 0; nf < 4; ++nf) {
            float v = ba0;
#pragma unroll
            for (int wmm = 0; wmm < 4; ++wmm) v += sred[wmm * 2 + wid][nf][n_];
            scores[(size_t)b * C_ + ct * CT + wid * 64 + nf * 16 + n_] = v;
        }
    }
}

// ---------------- fused: softmax over C  +  weighted[b][l] = sum_c w[c]*att[b][l][c] ----------------
__global__ __launch_bounds__(512) void k_fused(const float* __restrict__ att, const float* __restrict__ sc,
                                               float* __restrict__ out) {
    __shared__ float w_s[C_];
    __shared__ float red[8], red2[8];
    const int b = blockIdx.y, q = blockIdx.x;       // q: l-quarter 0..3
    const int t = threadIdx.x;
    const int lane = t & 63, wid = t >> 6;

    const float* sp = sc + (size_t)b * C_;
    float v[4];
#pragma unroll
    for (int j = 0; j < 4; ++j) v[j] = sp[j * 512 + t];
    float m = fmaxf(fmaxf(v[0], v[1]), fmaxf(v[2], v[3]));
#pragma unroll
    for (int off = 32; off >= 1; off >>= 1) m = fmaxf(m, __shfl_xor(m, off));
    if (lane == 0) red[wid] = m;
    __syncthreads();
#pragma unroll
    for (int w = 0; w < 8; ++w) m = fmaxf(m, red[w]);
    float s = 0.f;
#pragma unroll
    for (int j = 0; j < 4; ++j) {
        v[j] = __builtin_amdgcn_exp2f((v[j] - m) * 1.4426950408889634f);
        s += v[j];
    }
#pragma unroll
    for (int off = 32; off >= 1; off >>= 1) s += __shfl_xor(s, off);
    if (lane == 0) red2[wid] = s;
    __syncthreads();
    s = 0.f;
#pragma unroll
    for (int w = 0; w < 8; ++w) s += red2[w];
    float inv = 1.0f / s;
    float* wout = out + B_ * L_;
#pragma unroll
    for (int j = 0; j < 4; ++j) {
        float wv = v[j] * inv;
        w_s[j * 512 + t] = wv;
        if (q == 0) wout[(size_t)b * C_ + j * 512 + t] = wv;
    }
    __syncthreads();

    // weighted: 2 rows per wave concurrently for ILP
    for (int l0 = wid; l0 < 49; l0 += 16) {
        const int l1 = l0 + 8;
        const bool has1 = (l1 < 49);
        const float* ap0 = att + ((size_t)b * L_ + (q * 49 + l0)) * C_;
        const float* ap1 = att + ((size_t)b * L_ + (q * 49 + (has1 ? l1 : l0))) * C_;
        float a0 = 0.f, a1 = 0.f;
#pragma unroll
        for (int j = 0; j < 8; ++j) {
            int c = j * 256 + lane * 4;
            f32x4 x0 = *(const f32x4*)(ap0 + c);
            f32x4 x1 = *(const f32x4*)(ap1 + c);
            f32x4 w4 = *(const f32x4*)&w_s[c];
            a0 += x0[0] * w4[0] + x0[1] * w4[1] + x0[2] * w4[2] + x0[3] * w4[3];
            a1 += x1[0] * w4[0] + x1[1] * w4[1] + x1[2] * w4[2] + x1[3] * w4[3];
        }
#pragma unroll
        for (int off = 32; off >= 1; off >>= 1) {
            a0 += __shfl_xor(a0, off);
            a1 += __shfl_xor(a1, off);
        }
        if (lane == 0) {
            out[(size_t)b * L_ + q * 49 + l0] = a0;
            if (has1) out[(size_t)b * L_ + q * 49 + l1] = a1;
        }
    }
}

extern "C" void kernel_launch(void* const* d_in, const int* in_sizes, int n_in,
                              void* d_out, int out_size, void* d_ws, size_t ws_size,
                              hipStream_t stream) {
    const float* att = (const float*)d_in[0];
    const float* h   = (const float*)d_in[1];
    const float* Wc  = (const float*)d_in[2];
    const float* bc  = (const float*)d_in[3];
    const float* Wh  = (const float*)d_in[4];
    const float* bh  = (const float*)d_in[5];
    const float* wa  = (const float*)d_in[6];
    const float* ba  = (const float*)d_in[7];
    float* out = (float*)d_out;

    // workspace: ph (128*512 f32) | scores (128*2048 f32) | wcb3 (512*224 bf16)
    float* ph_ws  = (float*)d_ws;
    float* scores = ph_ws + B_ * H_;
    __bf16* wcb3  = (__bf16*)(scores + (size_t)B_ * C_);

    k_prep  <<<dim3(60), 512, 0, stream>>>(Wc, wcb3, h, Wh, bh, bc, ph_ws);
    k_scores<<<dim3(C_ / CT, B_), 512, 0, stream>>>(att, wcb3, ph_ws, wa, ba, scores);
    k_fused <<<dim3(4, B_), 512, 0, stream>>>(att, scores, out);
}